// Round 1
// baseline (2236.081 us; speedup 1.0000x reference)
//
#include <hip/hip_runtime.h>
#include <stdint.h>

#define M_DIM 8192
#define K_DIM 4096
#define N_DIM 16384
#define BM 128
#define BN 128
#define BK 32
#define LDA 40  // padded bf16 row stride for As (+8 halves -> 2-way max LDS conflict, free)

typedef __bf16 bf16x8 __attribute__((ext_vector_type(8)));
typedef float floatx4 __attribute__((ext_vector_type(4)));

union ABFrag { uint32_t u[4]; bf16x8 v; };

typedef const __attribute__((address_space(1))) void* gas_vp;
typedef __attribute__((address_space(3))) void* las_vp;

__device__ __forceinline__ uint32_t bfpack(float a, float b) {
    union { __bf16 h; uint16_t u; } ca, cb;
    ca.h = (__bf16)a; cb.h = (__bf16)b;
    return (uint32_t)ca.u | ((uint32_t)cb.u << 16);
}

// rowsum[m] = sum_k bf16(x[m,k])  -- feeds the zero-point & +128-offset epilogue terms
__global__ __launch_bounds__(256) void rowsum_kernel(const float* __restrict__ x,
                                                     float* __restrict__ rs) {
    const int m = blockIdx.x;
    const int t = threadIdx.x;
    const float4* row = (const float4*)(x + (size_t)m * K_DIM);
    float acc = 0.f;
#pragma unroll
    for (int r = 0; r < K_DIM / (256 * 4); ++r) {
        float4 v = row[r * 256 + t];
        acc += (float)(__bf16)v.x + (float)(__bf16)v.y
             + (float)(__bf16)v.z + (float)(__bf16)v.w;
    }
#pragma unroll
    for (int off = 32; off > 0; off >>= 1) acc += __shfl_down(acc, off, 64);
    __shared__ float sred[4];
    if ((t & 63) == 0) sred[t >> 6] = acc;
    __syncthreads();
    if (t == 0) rs[m] = sred[0] + sred[1] + sred[2] + sred[3];
}

__global__ __launch_bounds__(256, 3) void gemm4bit(
    const float* __restrict__ x,
    const int* __restrict__ packed,
    const float* __restrict__ scale,
    const float* __restrict__ zp,
    const float* __restrict__ bias,
    const float* __restrict__ rowsum,
    float* __restrict__ out) {

    __shared__ __bf16 As[BM][LDA];      // 10240 B, bf16 x-tile
    __shared__ uint32_t Bs[BM * 16];    // 8192 B, raw packed bytes (chunk-swizzled)

    const int tid  = threadIdx.x;
    const int lane = tid & 63;
    const int wv   = tid >> 6;          // 4 waves, 2x2
    const int wm   = wv >> 1;
    const int wn   = wv & 1;

    // supertile swizzle: 8 m-blocks x 16 n-blocks per supertile; m-sweep within n-supercolumn
    const int bid = blockIdx.x;
    const int sid = bid >> 7;
    const int lid = bid & 127;
    const int m_blk = (sid & 7) * 8 + (lid >> 4);
    const int n_blk = (sid >> 3) * 16 + (lid & 15);
    const int m0 = m_blk * BM;
    const int n0 = n_blk * BN;

    const int arow = tid >> 3;          // A staging: row within 32-row round
    const int akq  = tid & 7;           // float4 column

    const int col  = lane & 15;
    const int quad = lane >> 4;

    floatx4 acc[4][4];
#pragma unroll
    for (int i = 0; i < 4; ++i)
#pragma unroll
        for (int j = 0; j < 4; ++j) acc[i][j] = (floatx4){0.f, 0.f, 0.f, 0.f};

    const float* xbase = x + (size_t)m0 * K_DIM;

    for (int it = 0; it < K_DIM / BK; ++it) {
        const int k0 = it * BK;
        // ---- A stage: fp32 -> bf16 into padded LDS (4 rounds x float4/thread) ----
#pragma unroll
        for (int r = 0; r < 4; ++r) {
            const int row = r * 32 + arow;
            float4 v = *(const float4*)(xbase + (size_t)row * K_DIM + k0 + akq * 4);
            uint32_t d0 = bfpack(v.x, v.y);
            uint32_t d1 = bfpack(v.z, v.w);
            *(uint2*)&As[row][akq * 4] = make_uint2(d0, d1);
        }
        // ---- B stage: raw packed int32 via async global_load_lds (16B/lane) ----
        // LDS chunk swizzle: physical 16B-chunk p holds global chunk p ^ ((row>>1)&3)
#pragma unroll
        for (int r = 0; r < 2; ++r) {
            const int lin = (r * 4 + wv) * 64 + lane;   // 0..511
            const int row = lin >> 2;
            const int p   = lin & 3;
            const int c   = p ^ ((row >> 1) & 3);
            const int* gp = packed + (size_t)(n0 + row) * (K_DIM / 2) + it * 16 + c * 4;
            uint32_t* lp  = &Bs[(r * 4 + wv) * 256];    // wave-uniform base
            __builtin_amdgcn_global_load_lds((gas_vp)gp, (las_vp)lp, 16, 0, 0);
        }
        __syncthreads();

        // ---- fragments ----
        ABFrag a[4], b[4];
#pragma unroll
        for (int t = 0; t < 4; ++t) {
            const int mrow = wm * 64 + t * 16 + col;
            a[t].v = *(const bf16x8*)&As[mrow][quad * 8];

            const int nrow = wn * 64 + t * 16 + col;
            const int ch   = quad ^ ((nrow >> 1) & 3);
            uint4 w = *(const uint4*)&Bs[nrow * 16 + ch * 4];
            // nibble -> bf16(128+q): 0x4300 | q ; low nibble = even k, high = odd k
            b[t].u[0] = 0x43004300u | ((w.x & 0xF0u) << 12) | (w.x & 0x0Fu);
            b[t].u[1] = 0x43004300u | ((w.y & 0xF0u) << 12) | (w.y & 0x0Fu);
            b[t].u[2] = 0x43004300u | ((w.z & 0xF0u) << 12) | (w.z & 0x0Fu);
            b[t].u[3] = 0x43004300u | ((w.w & 0xF0u) << 12) | (w.w & 0x0Fu);
        }
#pragma unroll
        for (int tm = 0; tm < 4; ++tm)
#pragma unroll
            for (int tn = 0; tn < 4; ++tn)
                acc[tm][tn] = __builtin_amdgcn_mfma_f32_16x16x32_bf16(
                    a[tm].v, b[tn].v, acc[tm][tn], 0, 0, 0);
        __syncthreads();
    }

    // ---- epilogue: out = s*acc + (z - 128*s)*rowsum + bias ----
    float sv[4], av[4], bv[4];
#pragma unroll
    for (int tn = 0; tn < 4; ++tn) {
        const int n = n0 + wn * 64 + tn * 16 + col;
        const float s = scale[n];
        sv[tn] = s;
        av[tn] = zp[n] - 128.f * s;
        bv[tn] = bias[n];
    }
    float rsv[4][4];
#pragma unroll
    for (int tm = 0; tm < 4; ++tm)
#pragma unroll
        for (int r = 0; r < 4; ++r)
            rsv[tm][r] = rowsum[m0 + wm * 64 + tm * 16 + quad * 4 + r];

#pragma unroll
    for (int tm = 0; tm < 4; ++tm) {
#pragma unroll
        for (int r = 0; r < 4; ++r) {
            const int m = m0 + wm * 64 + tm * 16 + quad * 4 + r;
            float* orow = out + (size_t)m * N_DIM + n0 + wn * 64 + col;
#pragma unroll
            for (int tn = 0; tn < 4; ++tn) {
                orow[tn * 16] = sv[tn] * acc[tm][tn][r] + av[tn] * rsv[tm][r] + bv[tn];
            }
        }
    }
}

extern "C" void kernel_launch(void* const* d_in, const int* in_sizes, int n_in,
                              void* d_out, int out_size, void* d_ws, size_t ws_size,
                              hipStream_t stream) {
    const float* x      = (const float*)d_in[0];
    const int*   packed = (const int*)d_in[1];
    const float* scale  = (const float*)d_in[2];
    const float* zp     = (const float*)d_in[3];
    const float* bias   = (const float*)d_in[4];
    float* out = (float*)d_out;
    float* rs  = (float*)d_ws;  // 8192 floats = 32 KB of workspace

    rowsum_kernel<<<M_DIM, 256, 0, stream>>>(x, rs);
    gemm4bit<<<(M_DIM / BM) * (N_DIM / BN), 256, 0, stream>>>(
        x, packed, scale, zp, bias, rs, out);
}